// Round 1
// baseline (657.195 us; speedup 1.0000x reference)
//
#include <hip/hip_runtime.h>
#include <hip/hip_bf16.h>
#include <math.h>

#define NCH 32

typedef unsigned short ushort_t;
typedef unsigned int uint_t;
typedef unsigned char uchar_t;

static __device__ __forceinline__ float bf2f(ushort_t b) {
    return __uint_as_float(((uint_t)b) << 16);
}
static __device__ __forceinline__ ushort_t f2bf(float f) {
    __hip_bfloat16 h = __float2bfloat16(f);
    return *reinterpret_cast<ushort_t*>(&h);
}

using f32x2 = __attribute__((ext_vector_type(2))) float;

// ===========================================================================
// Round-14: CSR pull restructure.
//   r13 post-mortem: k_apply_pk is traffic-bound by construction — 102 MB of
//   device-scope pk-bf16 atomics (bypass non-coherent per-XCD L2) + two
//   random gather streams (12.8 MB working set >> 4 MB L2/XCD). Stats pass
//   has the same dual-gather structure.
//   Fix: counting-sort edges by src (deg hist fused into k_uv, 1-block scan,
//   4B-per-edge scatter), then:
//     - stats: per-node factorization  Σy = Σ deg·u + Σv ; Σy² = Σ deg·u²
//       + 2u·Σv + Σv²  → single fp8 gather stream (3.2 MB, L2-resident).
//     - apply: per-node loop, u read once, single vh gather stream (6.4 MB),
//       fp32 register accumulation, ONE coalesced fp32 store per node.
//       No atomics, no outh memset, no k_cvt.
// ===========================================================================

// --- per-node uh,vh (bf16) + vq (fp8 e4m3), fused src-degree histogram -----
__global__ __launch_bounds__(256) void k_uv_hist(
    const float* __restrict__ x, const float* __restrict__ W,
    ushort_t* __restrict__ uh, ushort_t* __restrict__ vh,
    uchar_t* __restrict__ vq,
    const int* __restrict__ srci, int* __restrict__ deg, int N, int E)
{
    __shared__ float At[NCH * NCH];   // At[k*32+c] = W[c][k] - W[c][32+k]
    __shared__ float Bt[NCH * NCH];   // Bt[k*32+c] = W[c][32+k]
    for (int i = threadIdx.x; i < NCH * NCH; i += 256) {
        const int k = i >> 5, c = i & 31;
        const float w1 = W[c * 64 + k];
        const float w2 = W[c * 64 + 32 + k];
        At[i] = w1 - w2;
        Bt[i] = w2;
    }
    __syncthreads();

    const int n = blockIdx.x * 8 + (threadIdx.x >> 5);
    const int c = threadIdx.x & 31;
    if (n < N) {
        const float xc = x[(size_t)n * NCH + c];
        float su = 0.f, sv = 0.f;
#pragma unroll
        for (int k = 0; k < NCH; ++k) {
            const float xk = __shfl(xc, k, 32);
            su = fmaf(At[k * 32 + c], xk, su);
            sv = fmaf(Bt[k * 32 + c], xk, sv);
        }
        uh[(size_t)n * NCH + c] = f2bf(su);
        vh[(size_t)n * NCH + c] = f2bf(sv);
        vq[(size_t)n * NCH + c] =
            (uchar_t)(__builtin_amdgcn_cvt_pk_fp8_f32(sv, sv, 0, false) & 0xFF);
    }

    // fused degree histogram over src (independent of the uv part)
    const int stride = gridDim.x * 256;
    for (int e = blockIdx.x * 256 + threadIdx.x; e < E; e += stride)
        atomicAdd(&deg[srci[e]], 1);
}

// --- single-block exclusive scan of deg -> row_start (N+1) + cursor copy ---
__global__ __launch_bounds__(1024) void k_scan(
    const int* __restrict__ deg, int* __restrict__ row_start,
    int* __restrict__ cursor, int N)
{
    __shared__ int wsum[16];
    __shared__ int wpre[16];
    const int t = threadIdx.x;
    const int lane = t & 63, wid = t >> 6;
    const int per = (N + 1023) >> 10;
    const int b = t * per;
    const int e = (b + per < N) ? (b + per) : N;

    int s = 0;
    for (int i = b; i < e; ++i) s += deg[i];

    // inclusive scan of per-thread sums within each wave
    int v = s;
#pragma unroll
    for (int off = 1; off < 64; off <<= 1) {
        int nv = __shfl_up(v, off, 64);
        if (lane >= off) v += nv;
    }
    if (lane == 63) wsum[wid] = v;
    __syncthreads();
    if (t == 0) {
        int acc = 0;
#pragma unroll
        for (int w = 0; w < 16; ++w) { wpre[w] = acc; acc += wsum[w]; }
    }
    __syncthreads();

    int run = wpre[wid] + v - s;   // exclusive prefix for this thread's chunk
    for (int i = b; i < e; ++i) {
        const int d = deg[i];
        row_start[i] = run;
        cursor[i] = run;
        run += d;
    }
    if (t == 1023) row_start[N] = run;   // == E (last chunk ends at N)
}

// --- scatter tgt into CSR slots (4B per edge vs 64B of atomics before) -----
__global__ __launch_bounds__(256) void k_scatter(
    const int* __restrict__ srci, const int* __restrict__ tgti,
    int* __restrict__ cursor, int* __restrict__ csr, int E)
{
    const int e = blockIdx.x * 256 + threadIdx.x;
    if (e >= E) return;
    const int s = srci[e], t = tgti[e];
    const int pos = atomicAdd(&cursor[s], 1);
    csr[pos] = t;
}

// --- stats via per-node factorization over fp8 v: 16-lane group per node ---
__global__ __launch_bounds__(256) void k_stats_csr(
    const ushort_t* __restrict__ uh, const uchar_t* __restrict__ vq,
    const int* __restrict__ row_start, const int* __restrict__ csr,
    float* __restrict__ partials, int N)
{
    const uint_t* __restrict__ uh32 = (const uint_t*)uh;
    const ushort_t* __restrict__ vq16 = (const ushort_t*)vq;
    const int l   = threadIdx.x & 15;    // channel pair (2l, 2l+1)
    const int grp = threadIdx.x >> 4;
    const int G  = blockIdx.x * 16 + grp;
    const int nG = gridDim.x * 16;

    float s0 = 0.f, s1 = 0.f, q0 = 0.f, q1 = 0.f;
    for (int n = G; n < N; n += nG) {
        const int r0 = row_start[n], r1 = row_start[n + 1];
        const uint_t U = uh32[(size_t)n * 16 + l];
        const float u0 = bf2f((ushort_t)(U & 0xFFFF));
        const float u1 = bf2f((ushort_t)(U >> 16));
        float sv0 = 0.f, sv1 = 0.f, vv0 = 0.f, vv1 = 0.f;
        int j = r0;
        for (; j + 1 < r1; j += 2) {
            const int ta = csr[j], tb = csr[j + 1];
            const f32x2 va = __builtin_amdgcn_cvt_pk_f32_fp8((int)vq16[(size_t)ta * 16 + l], false);
            const f32x2 vb = __builtin_amdgcn_cvt_pk_f32_fp8((int)vq16[(size_t)tb * 16 + l], false);
            sv0 += va.x + vb.x;
            sv1 += va.y + vb.y;
            vv0 = fmaf(va.x, va.x, vv0); vv0 = fmaf(vb.x, vb.x, vv0);
            vv1 = fmaf(va.y, va.y, vv1); vv1 = fmaf(vb.y, vb.y, vv1);
        }
        if (j < r1) {
            const f32x2 va = __builtin_amdgcn_cvt_pk_f32_fp8((int)vq16[(size_t)csr[j] * 16 + l], false);
            sv0 += va.x; sv1 += va.y;
            vv0 = fmaf(va.x, va.x, vv0);
            vv1 = fmaf(va.y, va.y, vv1);
        }
        const float d = (float)(r1 - r0);
        // sum y   = d*u + sv ;  sum y^2 = d*u^2 + 2u*sv + sv2
        s0 += fmaf(d, u0, sv0);
        s1 += fmaf(d, u1, sv1);
        q0 += fmaf(d, u0 * u0, fmaf(2.f * u0, sv0, vv0));
        q1 += fmaf(d, u1 * u1, fmaf(2.f * u1, sv1, vv1));
    }

    __shared__ float sL[16][32];
    __shared__ float qL[16][32];
    sL[grp][2 * l + 0] = s0;
    sL[grp][2 * l + 1] = s1;
    qL[grp][2 * l + 0] = q0;
    qL[grp][2 * l + 1] = q1;
    __syncthreads();
    if (threadIdx.x < 32) {
        float a = 0.f;
#pragma unroll
        for (int r = 0; r < 16; ++r) a += sL[r][threadIdx.x];
        partials[(size_t)blockIdx.x * 64 + threadIdx.x] = a;
    } else if (threadIdx.x < 64) {
        const int cc = threadIdx.x - 32;
        float a = 0.f;
#pragma unroll
        for (int r = 0; r < 16; ++r) a += qL[r][cc];
        partials[(size_t)blockIdx.x * 64 + 32 + cc] = a;
    }
}

// --- combine partials -> BN affine a,b -------------------------------------
__global__ __launch_bounds__(256) void k_finalize(
    const float* __restrict__ partials, int nblocks,
    const float* __restrict__ gamma, const float* __restrict__ beta,
    float* __restrict__ ab, float invE)
{
    __shared__ float acc[4][64];
    const int vtx = threadIdx.x & 63, chunk = threadIdx.x >> 6;
    float s = 0.f;
    for (int r = chunk; r < nblocks; r += 4) s += partials[(size_t)r * 64 + vtx];
    acc[chunk][vtx] = s;
    __syncthreads();
    if (threadIdx.x < 64) acc[0][vtx] = acc[0][vtx] + acc[1][vtx] + acc[2][vtx] + acc[3][vtx];
    __syncthreads();
    if (threadIdx.x < 32) {
        const int c = threadIdx.x;
        float mean = acc[0][c] * invE;
        float var  = acc[0][32 + c] * invE - mean * mean;
        float rstd = rsqrtf(var + 1e-5f);
        float a = gamma[c] * rstd;
        ab[c] = a; ab[32 + c] = beta[c] - mean * a;
    }
}

// --- apply: per-node pull, fp32 register accumulation, no atomics ----------
__global__ __launch_bounds__(256) void k_apply_csr(
    const ushort_t* __restrict__ uh, const ushort_t* __restrict__ vh,
    const int* __restrict__ row_start, const int* __restrict__ csr,
    const float* __restrict__ ab, float* __restrict__ out, int N)
{
    const uint_t* __restrict__ uh32 = (const uint_t*)uh;
    const uint_t* __restrict__ vh32 = (const uint_t*)vh;
    const int l   = threadIdx.x & 15;
    const int grp = threadIdx.x >> 4;
    const float a0 = ab[2 * l + 0], a1 = ab[2 * l + 1];
    const float b0 = ab[32 + 2 * l + 0], b1 = ab[32 + 2 * l + 1];
    const int G  = blockIdx.x * 16 + grp;
    const int nG = gridDim.x * 16;

    for (int n = G; n < N; n += nG) {
        const int r0 = row_start[n], r1 = row_start[n + 1];
        const uint_t U = uh32[(size_t)n * 16 + l];
        const float u0 = bf2f((ushort_t)(U & 0xFFFF));
        const float u1 = bf2f((ushort_t)(U >> 16));
        float acc0 = 0.f, acc1 = 0.f;
        int j = r0;
        for (; j + 1 < r1; j += 2) {
            const int ta = csr[j], tb = csr[j + 1];
            const uint_t Va = vh32[(size_t)ta * 16 + l];
            const uint_t Vb = vh32[(size_t)tb * 16 + l];
            float y0 = u0 + bf2f((ushort_t)(Va & 0xFFFF));
            float y1 = u1 + bf2f((ushort_t)(Va >> 16));
            float z0 = fmaf(a0, y0, b0);
            float z1 = fmaf(a1, y1, b1);
            z0 = (z0 > 0.f) ? z0 : (__expf(z0) - 1.0f);
            z1 = (z1 > 0.f) ? z1 : (__expf(z1) - 1.0f);
            acc0 += z0; acc1 += z1;
            y0 = u0 + bf2f((ushort_t)(Vb & 0xFFFF));
            y1 = u1 + bf2f((ushort_t)(Vb >> 16));
            z0 = fmaf(a0, y0, b0);
            z1 = fmaf(a1, y1, b1);
            z0 = (z0 > 0.f) ? z0 : (__expf(z0) - 1.0f);
            z1 = (z1 > 0.f) ? z1 : (__expf(z1) - 1.0f);
            acc0 += z0; acc1 += z1;
        }
        if (j < r1) {
            const uint_t Va = vh32[(size_t)csr[j] * 16 + l];
            float y0 = u0 + bf2f((ushort_t)(Va & 0xFFFF));
            float y1 = u1 + bf2f((ushort_t)(Va >> 16));
            float z0 = fmaf(a0, y0, b0);
            float z1 = fmaf(a1, y1, b1);
            z0 = (z0 > 0.f) ? z0 : (__expf(z0) - 1.0f);
            z1 = (z1 > 0.f) ? z1 : (__expf(z1) - 1.0f);
            acc0 += z0; acc1 += z1;
        }
        float2 o; o.x = acc0; o.y = acc1;
        ((float2*)out)[(size_t)n * 16 + l] = o;   // covers all n, incl. deg==0
    }
}

// ===========================================================================
// FALLBACK (round-1 proven path) — only if ws too small
// ===========================================================================
__global__ __launch_bounds__(256) void k_stats_hist(
    const float* __restrict__ x,
    const int* __restrict__ srci, const int* __restrict__ tgti,
    const float* __restrict__ W,
    float* __restrict__ partials, int E)
{
    float sum[NCH], ssq[NCH];
#pragma unroll
    for (int c = 0; c < NCH; ++c) { sum[c] = 0.f; ssq[c] = 0.f; }
    const int stride = gridDim.x * blockDim.x;
    for (int e = blockIdx.x * blockDim.x + threadIdx.x; e < E; e += stride) {
        const int s = srci[e], t = tgti[e];
        const float4* ps = (const float4*)(x + (size_t)s * NCH);
        const float4* pt = (const float4*)(x + (size_t)t * NCH);
        float xs[NCH], dx[NCH];
#pragma unroll
        for (int i = 0; i < 8; ++i) {
            float4 a = ps[i], bb = pt[i];
            xs[4*i+0] = a.x; xs[4*i+1] = a.y; xs[4*i+2] = a.z; xs[4*i+3] = a.w;
            dx[4*i+0] = bb.x - a.x; dx[4*i+1] = bb.y - a.y;
            dx[4*i+2] = bb.z - a.z; dx[4*i+3] = bb.w - a.w;
        }
#pragma unroll
        for (int c = 0; c < NCH; ++c) {
            const float* wr = W + c * 64;
            float y = 0.f;
#pragma unroll
            for (int k = 0; k < NCH; ++k) y = fmaf(wr[k], xs[k], y);
#pragma unroll
            for (int k = 0; k < NCH; ++k) y = fmaf(wr[32 + k], dx[k], y);
            sum[c] += y;
            ssq[c] = fmaf(y, y, ssq[c]);
        }
    }
#pragma unroll
    for (int c = 0; c < NCH; ++c) {
#pragma unroll
        for (int off = 32; off > 0; off >>= 1) {
            sum[c] += __shfl_down(sum[c], off);
            ssq[c] += __shfl_down(ssq[c], off);
        }
    }
    __shared__ float red[4][64];
    const int lane = threadIdx.x & 63, wave = threadIdx.x >> 6;
    if (lane == 0) {
#pragma unroll
        for (int c = 0; c < NCH; ++c) { red[wave][c] = sum[c]; red[wave][NCH+c] = ssq[c]; }
    }
    __syncthreads();
    if (threadIdx.x < 64)
        partials[(size_t)blockIdx.x * 64 + threadIdx.x] =
            red[0][threadIdx.x] + red[1][threadIdx.x] + red[2][threadIdx.x] + red[3][threadIdx.x];
}

__global__ __launch_bounds__(256) void k_apply_atomic(
    const float* __restrict__ x,
    const int* __restrict__ srci, const int* __restrict__ tgti,
    const float* __restrict__ W, const float* __restrict__ ab,
    float* __restrict__ out, int E)
{
    const int e = blockIdx.x * 256 + threadIdx.x;
    if (e >= E) return;
    const int s = srci[e], t = tgti[e];
    const float4* ps = (const float4*)(x + (size_t)s * NCH);
    const float4* pt = (const float4*)(x + (size_t)t * NCH);
    float xs[NCH], dx[NCH];
#pragma unroll
    for (int i = 0; i < 8; ++i) {
        float4 a = ps[i], bb = pt[i];
        xs[4*i+0] = a.x; xs[4*i+1] = a.y; xs[4*i+2] = a.z; xs[4*i+3] = a.w;
        dx[4*i+0] = bb.x - a.x; dx[4*i+1] = bb.y - a.y;
        dx[4*i+2] = bb.z - a.z; dx[4*i+3] = bb.w - a.w;
    }
    float* orow = out + (size_t)s * NCH;
#pragma unroll
    for (int c = 0; c < NCH; ++c) {
        const float* wr = W + c * 64;
        float y = 0.f;
#pragma unroll
        for (int k = 0; k < NCH; ++k) y = fmaf(wr[k], xs[k], y);
#pragma unroll
        for (int k = 0; k < NCH; ++k) y = fmaf(wr[32 + k], dx[k], y);
        float z = fmaf(ab[c], y, ab[32 + c]);
        z = (z > 0.f) ? z : (__expf(z) - 1.0f);
        atomicAdd(orow + c, z);
    }
}

// ===========================================================================
extern "C" void kernel_launch(void* const* d_in, const int* in_sizes, int n_in,
                              void* d_out, int out_size, void* d_ws, size_t ws_size,
                              hipStream_t stream)
{
    const float* x     = (const float*)d_in[0];
    const int*   ei    = (const int*)d_in[1];
    const float* W     = (const float*)d_in[2];
    const float* gamma = (const float*)d_in[3];
    const float* beta  = (const float*)d_in[4];
    const int E = in_sizes[1] / 2;
    const int N = in_sizes[0] / NCH;
    const int* srci = ei;
    const int* tgti = ei + E;

    const int SB = 1024;   // stats grid (16384 groups)
    const int AB = 2048;   // apply grid (32768 groups)

    // ws layout: uh,vh (bf16) | vq (fp8) | deg | row_start | cursor | csr
    //            | partials | ab
    ushort_t* uh      = (ushort_t*)d_ws;
    ushort_t* vh      = uh + (size_t)N * NCH;
    uchar_t*  vq      = (uchar_t*)(vh + (size_t)N * NCH);
    int*      deg     = (int*)(vq + (size_t)N * NCH);
    int*      row_start = deg + N;
    int*      cursor  = row_start + (N + 1);
    int*      csr     = cursor + N;
    float*    partials = (float*)(csr + E);
    float*    ab      = partials + (size_t)SB * 64;
    const size_t need = (size_t)((char*)(ab + 64) - (char*)d_ws);

    if (ws_size >= need) {
        hipMemsetAsync(deg, 0, (size_t)N * sizeof(int), stream);
        k_uv_hist<<<(N + 7) / 8, 256, 0, stream>>>(x, W, uh, vh, vq, srci, deg, N, E);
        k_scan<<<1, 1024, 0, stream>>>(deg, row_start, cursor, N);
        k_scatter<<<(E + 255) / 256, 256, 0, stream>>>(srci, tgti, cursor, csr, E);
        k_stats_csr<<<SB, 256, 0, stream>>>(uh, vq, row_start, csr, partials, N);
        k_finalize<<<1, 256, 0, stream>>>(partials, SB, gamma, beta, ab, 1.0f / (float)E);
        k_apply_csr<<<AB, 256, 0, stream>>>(uh, vh, row_start, csr, ab, (float*)d_out, N);
    } else {
        const int SBf = 512;
        float* abf      = (float*)d_ws;
        float* partialsf = abf + 64;
        hipMemsetAsync(d_out, 0, (size_t)out_size * sizeof(float), stream);
        k_stats_hist<<<SBf, 256, 0, stream>>>(x, srci, tgti, W, partialsf, E);
        k_finalize<<<1, 256, 0, stream>>>(partialsf, SBf, gamma, beta, abf, 1.0f / (float)E);
        k_apply_atomic<<<(E + 255) / 256, 256, 0, stream>>>(x, srci, tgti, W, abf,
                                                            (float*)d_out, E);
    }
}

// Round 2
// 446.770 us; speedup vs baseline: 1.4710x; 1.4710x over previous
//
#include <hip/hip_runtime.h>
#include <hip/hip_bf16.h>
#include <math.h>

#define NCH 32

typedef unsigned short ushort_t;
typedef unsigned int uint_t;
typedef unsigned char uchar_t;

static __device__ __forceinline__ float bf2f(ushort_t b) {
    return __uint_as_float(((uint_t)b) << 16);
}
static __device__ __forceinline__ ushort_t f2bf(float f) {
    __hip_bfloat16 h = __float2bfloat16(f);
    return *reinterpret_cast<ushort_t*>(&h);
}

using f32x2 = __attribute__((ext_vector_type(2))) float;

// ===========================================================================
// Round-15: fix the scan.
//   r14 post-mortem: CSR pull structure is sound (absmax 1.0->0.5, fp32
//   accumulation), but k_scan (ONE 1024-thread block, serial per-thread
//   loops over N=100K) measured 230 us/iter at 0.08% occupancy, plus a
//   30.8 ms first-touch-page-fault instance. Everything else is <230 us.
//   Fix: 3-kernel hierarchical scan (block-sums -> 1-block scan of ~391
//   block sums -> per-block scan+write). Parallel first-touch kills the
//   cold outlier. No other changes, so next profile exposes the true
//   scatter/stats/apply costs.
// ===========================================================================

// --- per-node uh,vh (bf16) + vq (fp8 e4m3), fused src-degree histogram -----
__global__ __launch_bounds__(256) void k_uv_hist(
    const float* __restrict__ x, const float* __restrict__ W,
    ushort_t* __restrict__ uh, ushort_t* __restrict__ vh,
    uchar_t* __restrict__ vq,
    const int* __restrict__ srci, int* __restrict__ deg, int N, int E)
{
    __shared__ float At[NCH * NCH];   // At[k*32+c] = W[c][k] - W[c][32+k]
    __shared__ float Bt[NCH * NCH];   // Bt[k*32+c] = W[c][32+k]
    for (int i = threadIdx.x; i < NCH * NCH; i += 256) {
        const int k = i >> 5, c = i & 31;
        const float w1 = W[c * 64 + k];
        const float w2 = W[c * 64 + 32 + k];
        At[i] = w1 - w2;
        Bt[i] = w2;
    }
    __syncthreads();

    const int n = blockIdx.x * 8 + (threadIdx.x >> 5);
    const int c = threadIdx.x & 31;
    if (n < N) {
        const float xc = x[(size_t)n * NCH + c];
        float su = 0.f, sv = 0.f;
#pragma unroll
        for (int k = 0; k < NCH; ++k) {
            const float xk = __shfl(xc, k, 32);
            su = fmaf(At[k * 32 + c], xk, su);
            sv = fmaf(Bt[k * 32 + c], xk, sv);
        }
        uh[(size_t)n * NCH + c] = f2bf(su);
        vh[(size_t)n * NCH + c] = f2bf(sv);
        vq[(size_t)n * NCH + c] =
            (uchar_t)(__builtin_amdgcn_cvt_pk_fp8_f32(sv, sv, 0, false) & 0xFF);
    }

    // fused degree histogram over src (independent of the uv part)
    const int stride = gridDim.x * 256;
    for (int e = blockIdx.x * 256 + threadIdx.x; e < E; e += stride)
        atomicAdd(&deg[srci[e]], 1);
}

// --- hierarchical scan, stage 1: per-256-block sums ------------------------
__global__ __launch_bounds__(256) void k_scan_bsum(
    const int* __restrict__ deg, int* __restrict__ bsum, int N)
{
    const int i = blockIdx.x * 256 + threadIdx.x;
    int d = (i < N) ? deg[i] : 0;
#pragma unroll
    for (int off = 32; off > 0; off >>= 1) d += __shfl_down(d, off, 64);
    __shared__ int w[4];
    if ((threadIdx.x & 63) == 0) w[threadIdx.x >> 6] = d;
    __syncthreads();
    if (threadIdx.x == 0) bsum[blockIdx.x] = w[0] + w[1] + w[2] + w[3];
}

// --- stage 2: single-block exclusive scan of block sums (NB <= 1024) -------
__global__ __launch_bounds__(1024) void k_scan_boff(
    int* __restrict__ bsum, int NB, int* __restrict__ rowN, int Eval)
{
    const int t = threadIdx.x;
    const int lane = t & 63;
    const int s = (t < NB) ? bsum[t] : 0;
    int v = s;
#pragma unroll
    for (int off = 1; off < 64; off <<= 1) {
        int nv = __shfl_up(v, off, 64);
        if (lane >= off) v += nv;
    }
    __shared__ int ws[16];
    __shared__ int wp[16];
    if (lane == 63) ws[t >> 6] = v;
    __syncthreads();
    if (t == 0) {
        int a = 0;
#pragma unroll
        for (int w = 0; w < 16; ++w) { wp[w] = a; a += ws[w]; }
    }
    __syncthreads();
    if (t < NB) bsum[t] = wp[t >> 6] + v - s;   // exclusive block offset
    if (t == 0) *rowN = Eval;                   // row_start[N] == E
}

// --- stage 3: per-block scan + add block offset; write row_start & cursor --
__global__ __launch_bounds__(256) void k_scan_write(
    const int* __restrict__ deg, const int* __restrict__ boff,
    int* __restrict__ row_start, int* __restrict__ cursor, int N)
{
    const int i = blockIdx.x * 256 + threadIdx.x;
    const int t = threadIdx.x;
    const int lane = t & 63;
    const int d = (i < N) ? deg[i] : 0;
    int v = d;
#pragma unroll
    for (int off = 1; off < 64; off <<= 1) {
        int nv = __shfl_up(v, off, 64);
        if (lane >= off) v += nv;
    }
    __shared__ int ws[4];
    __shared__ int wp[4];
    if (lane == 63) ws[t >> 6] = v;
    __syncthreads();
    if (t == 0) {
        int a = 0;
#pragma unroll
        for (int w = 0; w < 4; ++w) { wp[w] = a; a += ws[w]; }
    }
    __syncthreads();
    if (i < N) {
        const int ex = boff[blockIdx.x] + wp[t >> 6] + v - d;
        row_start[i] = ex;
        cursor[i] = ex;
    }
}

// --- fallback single-block scan (only if NB > 1024; not expected) ----------
__global__ __launch_bounds__(1024) void k_scan(
    const int* __restrict__ deg, int* __restrict__ row_start,
    int* __restrict__ cursor, int N)
{
    __shared__ int wsum[16];
    __shared__ int wpre[16];
    const int t = threadIdx.x;
    const int lane = t & 63, wid = t >> 6;
    const int per = (N + 1023) >> 10;
    const int b = t * per;
    const int e = (b + per < N) ? (b + per) : N;

    int s = 0;
    for (int i = b; i < e; ++i) s += deg[i];
    int v = s;
#pragma unroll
    for (int off = 1; off < 64; off <<= 1) {
        int nv = __shfl_up(v, off, 64);
        if (lane >= off) v += nv;
    }
    if (lane == 63) wsum[wid] = v;
    __syncthreads();
    if (t == 0) {
        int acc = 0;
#pragma unroll
        for (int w = 0; w < 16; ++w) { wpre[w] = acc; acc += wsum[w]; }
    }
    __syncthreads();
    int run = wpre[wid] + v - s;
    for (int i = b; i < e; ++i) {
        const int d = deg[i];
        row_start[i] = run;
        cursor[i] = run;
        run += d;
    }
    if (t == 1023) row_start[N] = run;
}

// --- scatter tgt into CSR slots (4B per edge vs 64B of atomics before) -----
__global__ __launch_bounds__(256) void k_scatter(
    const int* __restrict__ srci, const int* __restrict__ tgti,
    int* __restrict__ cursor, int* __restrict__ csr, int E)
{
    const int e = blockIdx.x * 256 + threadIdx.x;
    if (e >= E) return;
    const int s = srci[e], t = tgti[e];
    const int pos = atomicAdd(&cursor[s], 1);
    csr[pos] = t;
}

// --- stats via per-node factorization over fp8 v: 16-lane group per node ---
__global__ __launch_bounds__(256) void k_stats_csr(
    const ushort_t* __restrict__ uh, const uchar_t* __restrict__ vq,
    const int* __restrict__ row_start, const int* __restrict__ csr,
    float* __restrict__ partials, int N)
{
    const uint_t* __restrict__ uh32 = (const uint_t*)uh;
    const ushort_t* __restrict__ vq16 = (const ushort_t*)vq;
    const int l   = threadIdx.x & 15;    // channel pair (2l, 2l+1)
    const int grp = threadIdx.x >> 4;
    const int G  = blockIdx.x * 16 + grp;
    const int nG = gridDim.x * 16;

    float s0 = 0.f, s1 = 0.f, q0 = 0.f, q1 = 0.f;
    for (int n = G; n < N; n += nG) {
        const int r0 = row_start[n], r1 = row_start[n + 1];
        const uint_t U = uh32[(size_t)n * 16 + l];
        const float u0 = bf2f((ushort_t)(U & 0xFFFF));
        const float u1 = bf2f((ushort_t)(U >> 16));
        float sv0 = 0.f, sv1 = 0.f, vv0 = 0.f, vv1 = 0.f;
        int j = r0;
        for (; j + 1 < r1; j += 2) {
            const int ta = csr[j], tb = csr[j + 1];
            const f32x2 va = __builtin_amdgcn_cvt_pk_f32_fp8((int)vq16[(size_t)ta * 16 + l], false);
            const f32x2 vb = __builtin_amdgcn_cvt_pk_f32_fp8((int)vq16[(size_t)tb * 16 + l], false);
            sv0 += va.x + vb.x;
            sv1 += va.y + vb.y;
            vv0 = fmaf(va.x, va.x, vv0); vv0 = fmaf(vb.x, vb.x, vv0);
            vv1 = fmaf(va.y, va.y, vv1); vv1 = fmaf(vb.y, vb.y, vv1);
        }
        if (j < r1) {
            const f32x2 va = __builtin_amdgcn_cvt_pk_f32_fp8((int)vq16[(size_t)csr[j] * 16 + l], false);
            sv0 += va.x; sv1 += va.y;
            vv0 = fmaf(va.x, va.x, vv0);
            vv1 = fmaf(va.y, va.y, vv1);
        }
        const float d = (float)(r1 - r0);
        // sum y   = d*u + sv ;  sum y^2 = d*u^2 + 2u*sv + sv2
        s0 += fmaf(d, u0, sv0);
        s1 += fmaf(d, u1, sv1);
        q0 += fmaf(d, u0 * u0, fmaf(2.f * u0, sv0, vv0));
        q1 += fmaf(d, u1 * u1, fmaf(2.f * u1, sv1, vv1));
    }

    __shared__ float sL[16][32];
    __shared__ float qL[16][32];
    sL[grp][2 * l + 0] = s0;
    sL[grp][2 * l + 1] = s1;
    qL[grp][2 * l + 0] = q0;
    qL[grp][2 * l + 1] = q1;
    __syncthreads();
    if (threadIdx.x < 32) {
        float a = 0.f;
#pragma unroll
        for (int r = 0; r < 16; ++r) a += sL[r][threadIdx.x];
        partials[(size_t)blockIdx.x * 64 + threadIdx.x] = a;
    } else if (threadIdx.x < 64) {
        const int cc = threadIdx.x - 32;
        float a = 0.f;
#pragma unroll
        for (int r = 0; r < 16; ++r) a += qL[r][cc];
        partials[(size_t)blockIdx.x * 64 + 32 + cc] = a;
    }
}

// --- combine partials -> BN affine a,b -------------------------------------
__global__ __launch_bounds__(256) void k_finalize(
    const float* __restrict__ partials, int nblocks,
    const float* __restrict__ gamma, const float* __restrict__ beta,
    float* __restrict__ ab, float invE)
{
    __shared__ float acc[4][64];
    const int vtx = threadIdx.x & 63, chunk = threadIdx.x >> 6;
    float s = 0.f;
    for (int r = chunk; r < nblocks; r += 4) s += partials[(size_t)r * 64 + vtx];
    acc[chunk][vtx] = s;
    __syncthreads();
    if (threadIdx.x < 64) acc[0][vtx] = acc[0][vtx] + acc[1][vtx] + acc[2][vtx] + acc[3][vtx];
    __syncthreads();
    if (threadIdx.x < 32) {
        const int c = threadIdx.x;
        float mean = acc[0][c] * invE;
        float var  = acc[0][32 + c] * invE - mean * mean;
        float rstd = rsqrtf(var + 1e-5f);
        float a = gamma[c] * rstd;
        ab[c] = a; ab[32 + c] = beta[c] - mean * a;
    }
}

// --- apply: per-node pull, fp32 register accumulation, no atomics ----------
__global__ __launch_bounds__(256) void k_apply_csr(
    const ushort_t* __restrict__ uh, const ushort_t* __restrict__ vh,
    const int* __restrict__ row_start, const int* __restrict__ csr,
    const float* __restrict__ ab, float* __restrict__ out, int N)
{
    const uint_t* __restrict__ uh32 = (const uint_t*)uh;
    const uint_t* __restrict__ vh32 = (const uint_t*)vh;
    const int l   = threadIdx.x & 15;
    const int grp = threadIdx.x >> 4;
    const float a0 = ab[2 * l + 0], a1 = ab[2 * l + 1];
    const float b0 = ab[32 + 2 * l + 0], b1 = ab[32 + 2 * l + 1];
    const int G  = blockIdx.x * 16 + grp;
    const int nG = gridDim.x * 16;

    for (int n = G; n < N; n += nG) {
        const int r0 = row_start[n], r1 = row_start[n + 1];
        const uint_t U = uh32[(size_t)n * 16 + l];
        const float u0 = bf2f((ushort_t)(U & 0xFFFF));
        const float u1 = bf2f((ushort_t)(U >> 16));
        float acc0 = 0.f, acc1 = 0.f;
        int j = r0;
        for (; j + 1 < r1; j += 2) {
            const int ta = csr[j], tb = csr[j + 1];
            const uint_t Va = vh32[(size_t)ta * 16 + l];
            const uint_t Vb = vh32[(size_t)tb * 16 + l];
            float y0 = u0 + bf2f((ushort_t)(Va & 0xFFFF));
            float y1 = u1 + bf2f((ushort_t)(Va >> 16));
            float z0 = fmaf(a0, y0, b0);
            float z1 = fmaf(a1, y1, b1);
            z0 = (z0 > 0.f) ? z0 : (__expf(z0) - 1.0f);
            z1 = (z1 > 0.f) ? z1 : (__expf(z1) - 1.0f);
            acc0 += z0; acc1 += z1;
            y0 = u0 + bf2f((ushort_t)(Vb & 0xFFFF));
            y1 = u1 + bf2f((ushort_t)(Vb >> 16));
            z0 = fmaf(a0, y0, b0);
            z1 = fmaf(a1, y1, b1);
            z0 = (z0 > 0.f) ? z0 : (__expf(z0) - 1.0f);
            z1 = (z1 > 0.f) ? z1 : (__expf(z1) - 1.0f);
            acc0 += z0; acc1 += z1;
        }
        if (j < r1) {
            const uint_t Va = vh32[(size_t)csr[j] * 16 + l];
            float y0 = u0 + bf2f((ushort_t)(Va & 0xFFFF));
            float y1 = u1 + bf2f((ushort_t)(Va >> 16));
            float z0 = fmaf(a0, y0, b0);
            float z1 = fmaf(a1, y1, b1);
            z0 = (z0 > 0.f) ? z0 : (__expf(z0) - 1.0f);
            z1 = (z1 > 0.f) ? z1 : (__expf(z1) - 1.0f);
            acc0 += z0; acc1 += z1;
        }
        float2 o; o.x = acc0; o.y = acc1;
        ((float2*)out)[(size_t)n * 16 + l] = o;   // covers all n, incl. deg==0
    }
}

// ===========================================================================
// FALLBACK (round-1 proven path) — only if ws too small
// ===========================================================================
__global__ __launch_bounds__(256) void k_stats_hist(
    const float* __restrict__ x,
    const int* __restrict__ srci, const int* __restrict__ tgti,
    const float* __restrict__ W,
    float* __restrict__ partials, int E)
{
    float sum[NCH], ssq[NCH];
#pragma unroll
    for (int c = 0; c < NCH; ++c) { sum[c] = 0.f; ssq[c] = 0.f; }
    const int stride = gridDim.x * blockDim.x;
    for (int e = blockIdx.x * blockDim.x + threadIdx.x; e < E; e += stride) {
        const int s = srci[e], t = tgti[e];
        const float4* ps = (const float4*)(x + (size_t)s * NCH);
        const float4* pt = (const float4*)(x + (size_t)t * NCH);
        float xs[NCH], dx[NCH];
#pragma unroll
        for (int i = 0; i < 8; ++i) {
            float4 a = ps[i], bb = pt[i];
            xs[4*i+0] = a.x; xs[4*i+1] = a.y; xs[4*i+2] = a.z; xs[4*i+3] = a.w;
            dx[4*i+0] = bb.x - a.x; dx[4*i+1] = bb.y - a.y;
            dx[4*i+2] = bb.z - a.z; dx[4*i+3] = bb.w - a.w;
        }
#pragma unroll
        for (int c = 0; c < NCH; ++c) {
            const float* wr = W + c * 64;
            float y = 0.f;
#pragma unroll
            for (int k = 0; k < NCH; ++k) y = fmaf(wr[k], xs[k], y);
#pragma unroll
            for (int k = 0; k < NCH; ++k) y = fmaf(wr[32 + k], dx[k], y);
            sum[c] += y;
            ssq[c] = fmaf(y, y, ssq[c]);
        }
    }
#pragma unroll
    for (int c = 0; c < NCH; ++c) {
#pragma unroll
        for (int off = 32; off > 0; off >>= 1) {
            sum[c] += __shfl_down(sum[c], off);
            ssq[c] += __shfl_down(ssq[c], off);
        }
    }
    __shared__ float red[4][64];
    const int lane = threadIdx.x & 63, wave = threadIdx.x >> 6;
    if (lane == 0) {
#pragma unroll
        for (int c = 0; c < NCH; ++c) { red[wave][c] = sum[c]; red[wave][NCH+c] = ssq[c]; }
    }
    __syncthreads();
    if (threadIdx.x < 64)
        partials[(size_t)blockIdx.x * 64 + threadIdx.x] =
            red[0][threadIdx.x] + red[1][threadIdx.x] + red[2][threadIdx.x] + red[3][threadIdx.x];
}

__global__ __launch_bounds__(256) void k_apply_atomic(
    const float* __restrict__ x,
    const int* __restrict__ srci, const int* __restrict__ tgti,
    const float* __restrict__ W, const float* __restrict__ ab,
    float* __restrict__ out, int E)
{
    const int e = blockIdx.x * 256 + threadIdx.x;
    if (e >= E) return;
    const int s = srci[e], t = tgti[e];
    const float4* ps = (const float4*)(x + (size_t)s * NCH);
    const float4* pt = (const float4*)(x + (size_t)t * NCH);
    float xs[NCH], dx[NCH];
#pragma unroll
    for (int i = 0; i < 8; ++i) {
        float4 a = ps[i], bb = pt[i];
        xs[4*i+0] = a.x; xs[4*i+1] = a.y; xs[4*i+2] = a.z; xs[4*i+3] = a.w;
        dx[4*i+0] = bb.x - a.x; dx[4*i+1] = bb.y - a.y;
        dx[4*i+2] = bb.z - a.z; dx[4*i+3] = bb.w - a.w;
    }
    float* orow = out + (size_t)s * NCH;
#pragma unroll
    for (int c = 0; c < NCH; ++c) {
        const float* wr = W + c * 64;
        float y = 0.f;
#pragma unroll
        for (int k = 0; k < NCH; ++k) y = fmaf(wr[k], xs[k], y);
#pragma unroll
        for (int k = 0; k < NCH; ++k) y = fmaf(wr[32 + k], dx[k], y);
        float z = fmaf(ab[c], y, ab[32 + c]);
        z = (z > 0.f) ? z : (__expf(z) - 1.0f);
        atomicAdd(orow + c, z);
    }
}

// ===========================================================================
extern "C" void kernel_launch(void* const* d_in, const int* in_sizes, int n_in,
                              void* d_out, int out_size, void* d_ws, size_t ws_size,
                              hipStream_t stream)
{
    const float* x     = (const float*)d_in[0];
    const int*   ei    = (const int*)d_in[1];
    const float* W     = (const float*)d_in[2];
    const float* gamma = (const float*)d_in[3];
    const float* beta  = (const float*)d_in[4];
    const int E = in_sizes[1] / 2;
    const int N = in_sizes[0] / NCH;
    const int* srci = ei;
    const int* tgti = ei + E;

    const int SB = 1024;   // stats grid (16384 groups)
    const int AB = 2048;   // apply grid (32768 groups)
    const int NB = (N + 255) / 256;   // scan blocks

    // ws layout: uh,vh (bf16) | vq (fp8) | deg | row_start | cursor | csr
    //            | bsum | partials | ab
    ushort_t* uh      = (ushort_t*)d_ws;
    ushort_t* vh      = uh + (size_t)N * NCH;
    uchar_t*  vq      = (uchar_t*)(vh + (size_t)N * NCH);
    int*      deg     = (int*)(vq + (size_t)N * NCH);
    int*      row_start = deg + N;
    int*      cursor  = row_start + (N + 1);
    int*      csr     = cursor + N;
    int*      bsum    = csr + E;
    float*    partials = (float*)(bsum + NB);
    float*    ab      = partials + (size_t)SB * 64;
    const size_t need = (size_t)((char*)(ab + 64) - (char*)d_ws);

    if (ws_size >= need) {
        hipMemsetAsync(deg, 0, (size_t)N * sizeof(int), stream);
        k_uv_hist<<<(N + 7) / 8, 256, 0, stream>>>(x, W, uh, vh, vq, srci, deg, N, E);
        if (NB <= 1024) {
            k_scan_bsum<<<NB, 256, 0, stream>>>(deg, bsum, N);
            k_scan_boff<<<1, 1024, 0, stream>>>(bsum, NB, row_start + N, E);
            k_scan_write<<<NB, 256, 0, stream>>>(deg, bsum, row_start, cursor, N);
        } else {
            k_scan<<<1, 1024, 0, stream>>>(deg, row_start, cursor, N);
        }
        k_scatter<<<(E + 255) / 256, 256, 0, stream>>>(srci, tgti, cursor, csr, E);
        k_stats_csr<<<SB, 256, 0, stream>>>(uh, vq, row_start, csr, partials, N);
        k_finalize<<<1, 256, 0, stream>>>(partials, SB, gamma, beta, ab, 1.0f / (float)E);
        k_apply_csr<<<AB, 256, 0, stream>>>(uh, vh, row_start, csr, ab, (float*)d_out, N);
    } else {
        const int SBf = 512;
        float* abf      = (float*)d_ws;
        float* partialsf = abf + 64;
        hipMemsetAsync(d_out, 0, (size_t)out_size * sizeof(float), stream);
        k_stats_hist<<<SBf, 256, 0, stream>>>(x, srci, tgti, W, partialsf, E);
        k_finalize<<<1, 256, 0, stream>>>(partialsf, SBf, gamma, beta, abf, 1.0f / (float)E);
        k_apply_atomic<<<(E + 255) / 256, 256, 0, stream>>>(x, srci, tgti, W, abf,
                                                            (float*)d_out, E);
    }
}

// Round 3
// 372.552 us; speedup vs baseline: 1.7640x; 1.1992x over previous
//
#include <hip/hip_runtime.h>
#include <hip/hip_bf16.h>
#include <math.h>

#define NCH 32

typedef unsigned short ushort_t;
typedef unsigned int uint_t;
typedef unsigned char uchar_t;

static __device__ __forceinline__ float bf2f(ushort_t b) {
    return __uint_as_float(((uint_t)b) << 16);
}
static __device__ __forceinline__ ushort_t f2bf(float f) {
    __hip_bfloat16 h = __float2bfloat16(f);
    return *reinterpret_cast<ushort_t*>(&h);
}

using f32x2 = __attribute__((ext_vector_type(2))) float;

// ===========================================================================
// Round-16: XCD-local CSR scatter.
//   r15 post-mortem: k_scatter = 140 us, WRITE_SIZE = 105 MB — 64 B HBM
//   write-back per 4 B csr entry. Each 64 B csr line gets entries written
//   from blocks on all 8 XCDs; every non-coherent L2 evicts a partially
//   dirty copy (byte-masked) -> ~8x write amplification at 10% BW.
//   Fix: node-range bucketing + blockIdx%8 XCD round-robin heuristic.
//   Bucket x's csr byte range is contiguous and written ONLY by blocks
//   blockIdx&7==x -> lines dirty in exactly one L2, evict once, ~6.4 MB
//   writes. Cost: 8x srci re-read, absorbed by L3 (FETCH stays ~7 MB).
//   Same filter applied to the deg histogram in k_uv_hist.
// ===========================================================================

// --- per-node uh,vh (bf16) + vq (fp8 e4m3), fused XCD-local degree hist ----
__global__ __launch_bounds__(256) void k_uv_hist(
    const float* __restrict__ x, const float* __restrict__ W,
    ushort_t* __restrict__ uh, ushort_t* __restrict__ vh,
    uchar_t* __restrict__ vq,
    const int* __restrict__ srci, int* __restrict__ deg, int N, int E, int NS)
{
    __shared__ float At[NCH * NCH];   // At[k*32+c] = W[c][k] - W[c][32+k]
    __shared__ float Bt[NCH * NCH];   // Bt[k*32+c] = W[c][32+k]
    for (int i = threadIdx.x; i < NCH * NCH; i += 256) {
        const int k = i >> 5, c = i & 31;
        const float w1 = W[c * 64 + k];
        const float w2 = W[c * 64 + 32 + k];
        At[i] = w1 - w2;
        Bt[i] = w2;
    }
    __syncthreads();

    const int n = blockIdx.x * 8 + (threadIdx.x >> 5);
    const int c = threadIdx.x & 31;
    if (n < N) {
        const float xc = x[(size_t)n * NCH + c];
        float su = 0.f, sv = 0.f;
#pragma unroll
        for (int k = 0; k < NCH; ++k) {
            const float xk = __shfl(xc, k, 32);
            su = fmaf(At[k * 32 + c], xk, su);
            sv = fmaf(Bt[k * 32 + c], xk, sv);
        }
        uh[(size_t)n * NCH + c] = f2bf(su);
        vh[(size_t)n * NCH + c] = f2bf(sv);
        vq[(size_t)n * NCH + c] =
            (uchar_t)(__builtin_amdgcn_cvt_pk_fp8_f32(sv, sv, 0, false) & 0xFF);
    }

    // XCD-local degree histogram: bucket x = blockIdx&7 counts only nodes
    // in [x*NS, x*NS+NS) so deg lines are touched by one XCD's L2 only.
    const int xb = blockIdx.x & 7;
    const int lo = xb * NS;
    const int nb = (gridDim.x - xb + 7) >> 3;   // #blocks with blockIdx&7==xb
    const int bi = blockIdx.x >> 3;
    const int stride = nb * 256;
    for (int e = bi * 256 + threadIdx.x; e < E; e += stride) {
        const int s = srci[e];
        if ((unsigned)(s - lo) < (unsigned)NS) atomicAdd(&deg[s], 1);
    }
}

// --- hierarchical scan, stage 1: per-256-block sums ------------------------
__global__ __launch_bounds__(256) void k_scan_bsum(
    const int* __restrict__ deg, int* __restrict__ bsum, int N)
{
    const int i = blockIdx.x * 256 + threadIdx.x;
    int d = (i < N) ? deg[i] : 0;
#pragma unroll
    for (int off = 32; off > 0; off >>= 1) d += __shfl_down(d, off, 64);
    __shared__ int w[4];
    if ((threadIdx.x & 63) == 0) w[threadIdx.x >> 6] = d;
    __syncthreads();
    if (threadIdx.x == 0) bsum[blockIdx.x] = w[0] + w[1] + w[2] + w[3];
}

// --- stage 2: single-block exclusive scan of block sums (NB <= 1024) -------
__global__ __launch_bounds__(1024) void k_scan_boff(
    int* __restrict__ bsum, int NB, int* __restrict__ rowN, int Eval)
{
    const int t = threadIdx.x;
    const int lane = t & 63;
    const int s = (t < NB) ? bsum[t] : 0;
    int v = s;
#pragma unroll
    for (int off = 1; off < 64; off <<= 1) {
        int nv = __shfl_up(v, off, 64);
        if (lane >= off) v += nv;
    }
    __shared__ int ws[16];
    __shared__ int wp[16];
    if (lane == 63) ws[t >> 6] = v;
    __syncthreads();
    if (t == 0) {
        int a = 0;
#pragma unroll
        for (int w = 0; w < 16; ++w) { wp[w] = a; a += ws[w]; }
    }
    __syncthreads();
    if (t < NB) bsum[t] = wp[t >> 6] + v - s;   // exclusive block offset
    if (t == 0) *rowN = Eval;                   // row_start[N] == E
}

// --- stage 3: per-block scan + add block offset; write row_start & cursor --
__global__ __launch_bounds__(256) void k_scan_write(
    const int* __restrict__ deg, const int* __restrict__ boff,
    int* __restrict__ row_start, int* __restrict__ cursor, int N)
{
    const int i = blockIdx.x * 256 + threadIdx.x;
    const int t = threadIdx.x;
    const int lane = t & 63;
    const int d = (i < N) ? deg[i] : 0;
    int v = d;
#pragma unroll
    for (int off = 1; off < 64; off <<= 1) {
        int nv = __shfl_up(v, off, 64);
        if (lane >= off) v += nv;
    }
    __shared__ int ws[4];
    __shared__ int wp[4];
    if (lane == 63) ws[t >> 6] = v;
    __syncthreads();
    if (t == 0) {
        int a = 0;
#pragma unroll
        for (int w = 0; w < 4; ++w) { wp[w] = a; a += ws[w]; }
    }
    __syncthreads();
    if (i < N) {
        const int ex = boff[blockIdx.x] + wp[t >> 6] + v - d;
        row_start[i] = ex;
        cursor[i] = ex;
    }
}

// --- fallback single-block scan (only if NB > 1024; not expected) ----------
__global__ __launch_bounds__(1024) void k_scan(
    const int* __restrict__ deg, int* __restrict__ row_start,
    int* __restrict__ cursor, int N)
{
    __shared__ int wsum[16];
    __shared__ int wpre[16];
    const int t = threadIdx.x;
    const int lane = t & 63, wid = t >> 6;
    const int per = (N + 1023) >> 10;
    const int b = t * per;
    const int e = (b + per < N) ? (b + per) : N;

    int s = 0;
    for (int i = b; i < e; ++i) s += deg[i];
    int v = s;
#pragma unroll
    for (int off = 1; off < 64; off <<= 1) {
        int nv = __shfl_up(v, off, 64);
        if (lane >= off) v += nv;
    }
    if (lane == 63) wsum[wid] = v;
    __syncthreads();
    if (t == 0) {
        int acc = 0;
#pragma unroll
        for (int w = 0; w < 16; ++w) { wpre[w] = acc; acc += wsum[w]; }
    }
    __syncthreads();
    int run = wpre[wid] + v - s;
    for (int i = b; i < e; ++i) {
        const int d = deg[i];
        row_start[i] = run;
        cursor[i] = run;
        run += d;
    }
    if (t == 1023) row_start[N] = run;
}

// --- XCD-local scatter: bucket x (blockIdx&7) writes only its csr range ----
__global__ __launch_bounds__(256) void k_scatter_xcd(
    const int* __restrict__ srci, const int* __restrict__ tgti,
    int* __restrict__ cursor, int* __restrict__ csr, int E, int NS)
{
    const int xb = blockIdx.x & 7;
    const int lo = xb * NS;
    const int nb = gridDim.x >> 3;      // gridDim.x is a multiple of 8
    const int bi = blockIdx.x >> 3;
    const int stride = nb * 256;
    for (int e = bi * 256 + threadIdx.x; e < E; e += stride) {
        const int s = srci[e];
        if ((unsigned)(s - lo) < (unsigned)NS) {
            const int pos = atomicAdd(&cursor[s], 1);
            csr[pos] = tgti[e];
        }
    }
}

// --- stats via per-node factorization over fp8 v: 16-lane group per node ---
__global__ __launch_bounds__(256) void k_stats_csr(
    const ushort_t* __restrict__ uh, const uchar_t* __restrict__ vq,
    const int* __restrict__ row_start, const int* __restrict__ csr,
    float* __restrict__ partials, int N)
{
    const uint_t* __restrict__ uh32 = (const uint_t*)uh;
    const ushort_t* __restrict__ vq16 = (const ushort_t*)vq;
    const int l   = threadIdx.x & 15;    // channel pair (2l, 2l+1)
    const int grp = threadIdx.x >> 4;
    const int G  = blockIdx.x * 16 + grp;
    const int nG = gridDim.x * 16;

    float s0 = 0.f, s1 = 0.f, q0 = 0.f, q1 = 0.f;
    for (int n = G; n < N; n += nG) {
        const int r0 = row_start[n], r1 = row_start[n + 1];
        const uint_t U = uh32[(size_t)n * 16 + l];
        const float u0 = bf2f((ushort_t)(U & 0xFFFF));
        const float u1 = bf2f((ushort_t)(U >> 16));
        float sv0 = 0.f, sv1 = 0.f, vv0 = 0.f, vv1 = 0.f;
        int j = r0;
        for (; j + 1 < r1; j += 2) {
            const int ta = csr[j], tb = csr[j + 1];
            const f32x2 va = __builtin_amdgcn_cvt_pk_f32_fp8((int)vq16[(size_t)ta * 16 + l], false);
            const f32x2 vb = __builtin_amdgcn_cvt_pk_f32_fp8((int)vq16[(size_t)tb * 16 + l], false);
            sv0 += va.x + vb.x;
            sv1 += va.y + vb.y;
            vv0 = fmaf(va.x, va.x, vv0); vv0 = fmaf(vb.x, vb.x, vv0);
            vv1 = fmaf(va.y, va.y, vv1); vv1 = fmaf(vb.y, vb.y, vv1);
        }
        if (j < r1) {
            const f32x2 va = __builtin_amdgcn_cvt_pk_f32_fp8((int)vq16[(size_t)csr[j] * 16 + l], false);
            sv0 += va.x; sv1 += va.y;
            vv0 = fmaf(va.x, va.x, vv0);
            vv1 = fmaf(va.y, va.y, vv1);
        }
        const float d = (float)(r1 - r0);
        // sum y   = d*u + sv ;  sum y^2 = d*u^2 + 2u*sv + sv2
        s0 += fmaf(d, u0, sv0);
        s1 += fmaf(d, u1, sv1);
        q0 += fmaf(d, u0 * u0, fmaf(2.f * u0, sv0, vv0));
        q1 += fmaf(d, u1 * u1, fmaf(2.f * u1, sv1, vv1));
    }

    __shared__ float sL[16][32];
    __shared__ float qL[16][32];
    sL[grp][2 * l + 0] = s0;
    sL[grp][2 * l + 1] = s1;
    qL[grp][2 * l + 0] = q0;
    qL[grp][2 * l + 1] = q1;
    __syncthreads();
    if (threadIdx.x < 32) {
        float a = 0.f;
#pragma unroll
        for (int r = 0; r < 16; ++r) a += sL[r][threadIdx.x];
        partials[(size_t)blockIdx.x * 64 + threadIdx.x] = a;
    } else if (threadIdx.x < 64) {
        const int cc = threadIdx.x - 32;
        float a = 0.f;
#pragma unroll
        for (int r = 0; r < 16; ++r) a += qL[r][cc];
        partials[(size_t)blockIdx.x * 64 + 32 + cc] = a;
    }
}

// --- combine partials -> BN affine a,b -------------------------------------
__global__ __launch_bounds__(256) void k_finalize(
    const float* __restrict__ partials, int nblocks,
    const float* __restrict__ gamma, const float* __restrict__ beta,
    float* __restrict__ ab, float invE)
{
    __shared__ float acc[4][64];
    const int vtx = threadIdx.x & 63, chunk = threadIdx.x >> 6;
    float s = 0.f;
    for (int r = chunk; r < nblocks; r += 4) s += partials[(size_t)r * 64 + vtx];
    acc[chunk][vtx] = s;
    __syncthreads();
    if (threadIdx.x < 64) acc[0][vtx] = acc[0][vtx] + acc[1][vtx] + acc[2][vtx] + acc[3][vtx];
    __syncthreads();
    if (threadIdx.x < 32) {
        const int c = threadIdx.x;
        float mean = acc[0][c] * invE;
        float var  = acc[0][32 + c] * invE - mean * mean;
        float rstd = rsqrtf(var + 1e-5f);
        float a = gamma[c] * rstd;
        ab[c] = a; ab[32 + c] = beta[c] - mean * a;
    }
}

// --- apply: per-node pull, fp32 register accumulation, no atomics ----------
__global__ __launch_bounds__(256) void k_apply_csr(
    const ushort_t* __restrict__ uh, const ushort_t* __restrict__ vh,
    const int* __restrict__ row_start, const int* __restrict__ csr,
    const float* __restrict__ ab, float* __restrict__ out, int N)
{
    const uint_t* __restrict__ uh32 = (const uint_t*)uh;
    const uint_t* __restrict__ vh32 = (const uint_t*)vh;
    const int l   = threadIdx.x & 15;
    const int grp = threadIdx.x >> 4;
    const float a0 = ab[2 * l + 0], a1 = ab[2 * l + 1];
    const float b0 = ab[32 + 2 * l + 0], b1 = ab[32 + 2 * l + 1];
    const int G  = blockIdx.x * 16 + grp;
    const int nG = gridDim.x * 16;

    for (int n = G; n < N; n += nG) {
        const int r0 = row_start[n], r1 = row_start[n + 1];
        const uint_t U = uh32[(size_t)n * 16 + l];
        const float u0 = bf2f((ushort_t)(U & 0xFFFF));
        const float u1 = bf2f((ushort_t)(U >> 16));
        float acc0 = 0.f, acc1 = 0.f;
        int j = r0;
        for (; j + 1 < r1; j += 2) {
            const int ta = csr[j], tb = csr[j + 1];
            const uint_t Va = vh32[(size_t)ta * 16 + l];
            const uint_t Vb = vh32[(size_t)tb * 16 + l];
            float y0 = u0 + bf2f((ushort_t)(Va & 0xFFFF));
            float y1 = u1 + bf2f((ushort_t)(Va >> 16));
            float z0 = fmaf(a0, y0, b0);
            float z1 = fmaf(a1, y1, b1);
            z0 = (z0 > 0.f) ? z0 : (__expf(z0) - 1.0f);
            z1 = (z1 > 0.f) ? z1 : (__expf(z1) - 1.0f);
            acc0 += z0; acc1 += z1;
            y0 = u0 + bf2f((ushort_t)(Vb & 0xFFFF));
            y1 = u1 + bf2f((ushort_t)(Vb >> 16));
            z0 = fmaf(a0, y0, b0);
            z1 = fmaf(a1, y1, b1);
            z0 = (z0 > 0.f) ? z0 : (__expf(z0) - 1.0f);
            z1 = (z1 > 0.f) ? z1 : (__expf(z1) - 1.0f);
            acc0 += z0; acc1 += z1;
        }
        if (j < r1) {
            const uint_t Va = vh32[(size_t)csr[j] * 16 + l];
            float y0 = u0 + bf2f((ushort_t)(Va & 0xFFFF));
            float y1 = u1 + bf2f((ushort_t)(Va >> 16));
            float z0 = fmaf(a0, y0, b0);
            float z1 = fmaf(a1, y1, b1);
            z0 = (z0 > 0.f) ? z0 : (__expf(z0) - 1.0f);
            z1 = (z1 > 0.f) ? z1 : (__expf(z1) - 1.0f);
            acc0 += z0; acc1 += z1;
        }
        float2 o; o.x = acc0; o.y = acc1;
        ((float2*)out)[(size_t)n * 16 + l] = o;   // covers all n, incl. deg==0
    }
}

// ===========================================================================
// FALLBACK (round-1 proven path) — only if ws too small
// ===========================================================================
__global__ __launch_bounds__(256) void k_stats_hist(
    const float* __restrict__ x,
    const int* __restrict__ srci, const int* __restrict__ tgti,
    const float* __restrict__ W,
    float* __restrict__ partials, int E)
{
    float sum[NCH], ssq[NCH];
#pragma unroll
    for (int c = 0; c < NCH; ++c) { sum[c] = 0.f; ssq[c] = 0.f; }
    const int stride = gridDim.x * blockDim.x;
    for (int e = blockIdx.x * blockDim.x + threadIdx.x; e < E; e += stride) {
        const int s = srci[e], t = tgti[e];
        const float4* ps = (const float4*)(x + (size_t)s * NCH);
        const float4* pt = (const float4*)(x + (size_t)t * NCH);
        float xs[NCH], dx[NCH];
#pragma unroll
        for (int i = 0; i < 8; ++i) {
            float4 a = ps[i], bb = pt[i];
            xs[4*i+0] = a.x; xs[4*i+1] = a.y; xs[4*i+2] = a.z; xs[4*i+3] = a.w;
            dx[4*i+0] = bb.x - a.x; dx[4*i+1] = bb.y - a.y;
            dx[4*i+2] = bb.z - a.z; dx[4*i+3] = bb.w - a.w;
        }
#pragma unroll
        for (int c = 0; c < NCH; ++c) {
            const float* wr = W + c * 64;
            float y = 0.f;
#pragma unroll
            for (int k = 0; k < NCH; ++k) y = fmaf(wr[k], xs[k], y);
#pragma unroll
            for (int k = 0; k < NCH; ++k) y = fmaf(wr[32 + k], dx[k], y);
            sum[c] += y;
            ssq[c] = fmaf(y, y, ssq[c]);
        }
    }
#pragma unroll
    for (int c = 0; c < NCH; ++c) {
#pragma unroll
        for (int off = 32; off > 0; off >>= 1) {
            sum[c] += __shfl_down(sum[c], off);
            ssq[c] += __shfl_down(ssq[c], off);
        }
    }
    __shared__ float red[4][64];
    const int lane = threadIdx.x & 63, wave = threadIdx.x >> 6;
    if (lane == 0) {
#pragma unroll
        for (int c = 0; c < NCH; ++c) { red[wave][c] = sum[c]; red[wave][NCH+c] = ssq[c]; }
    }
    __syncthreads();
    if (threadIdx.x < 64)
        partials[(size_t)blockIdx.x * 64 + threadIdx.x] =
            red[0][threadIdx.x] + red[1][threadIdx.x] + red[2][threadIdx.x] + red[3][threadIdx.x];
}

__global__ __launch_bounds__(256) void k_apply_atomic(
    const float* __restrict__ x,
    const int* __restrict__ srci, const int* __restrict__ tgti,
    const float* __restrict__ W, const float* __restrict__ ab,
    float* __restrict__ out, int E)
{
    const int e = blockIdx.x * 256 + threadIdx.x;
    if (e >= E) return;
    const int s = srci[e], t = tgti[e];
    const float4* ps = (const float4*)(x + (size_t)s * NCH);
    const float4* pt = (const float4*)(x + (size_t)t * NCH);
    float xs[NCH], dx[NCH];
#pragma unroll
    for (int i = 0; i < 8; ++i) {
        float4 a = ps[i], bb = pt[i];
        xs[4*i+0] = a.x; xs[4*i+1] = a.y; xs[4*i+2] = a.z; xs[4*i+3] = a.w;
        dx[4*i+0] = bb.x - a.x; dx[4*i+1] = bb.y - a.y;
        dx[4*i+2] = bb.z - a.z; dx[4*i+3] = bb.w - a.w;
    }
    float* orow = out + (size_t)s * NCH;
#pragma unroll
    for (int c = 0; c < NCH; ++c) {
        const float* wr = W + c * 64;
        float y = 0.f;
#pragma unroll
        for (int k = 0; k < NCH; ++k) y = fmaf(wr[k], xs[k], y);
#pragma unroll
        for (int k = 0; k < NCH; ++k) y = fmaf(wr[32 + k], dx[k], y);
        float z = fmaf(ab[c], y, ab[32 + c]);
        z = (z > 0.f) ? z : (__expf(z) - 1.0f);
        atomicAdd(orow + c, z);
    }
}

// ===========================================================================
extern "C" void kernel_launch(void* const* d_in, const int* in_sizes, int n_in,
                              void* d_out, int out_size, void* d_ws, size_t ws_size,
                              hipStream_t stream)
{
    const float* x     = (const float*)d_in[0];
    const int*   ei    = (const int*)d_in[1];
    const float* W     = (const float*)d_in[2];
    const float* gamma = (const float*)d_in[3];
    const float* beta  = (const float*)d_in[4];
    const int E = in_sizes[1] / 2;
    const int N = in_sizes[0] / NCH;
    const int* srci = ei;
    const int* tgti = ei + E;

    const int SB = 1024;             // stats grid (16384 groups)
    const int AB = 2048;             // apply grid (32768 groups)
    const int NB = (N + 255) / 256;  // scan blocks
    const int NS = (N + 7) / 8;      // nodes per XCD bucket

    // ws layout: uh,vh (bf16) | vq (fp8) | deg | row_start | cursor | csr
    //            | bsum | partials | ab
    ushort_t* uh      = (ushort_t*)d_ws;
    ushort_t* vh      = uh + (size_t)N * NCH;
    uchar_t*  vq      = (uchar_t*)(vh + (size_t)N * NCH);
    int*      deg     = (int*)(vq + (size_t)N * NCH);
    int*      row_start = deg + N;
    int*      cursor  = row_start + (N + 1);
    int*      csr     = cursor + N;
    int*      bsum    = csr + E;
    float*    partials = (float*)(bsum + NB);
    float*    ab      = partials + (size_t)SB * 64;
    const size_t need = (size_t)((char*)(ab + 64) - (char*)d_ws);

    if (ws_size >= need && NB <= 1024) {
        hipMemsetAsync(deg, 0, (size_t)N * sizeof(int), stream);
        k_uv_hist<<<(N + 7) / 8, 256, 0, stream>>>(x, W, uh, vh, vq, srci, deg, N, E, NS);
        k_scan_bsum<<<NB, 256, 0, stream>>>(deg, bsum, N);
        k_scan_boff<<<1, 1024, 0, stream>>>(bsum, NB, row_start + N, E);
        k_scan_write<<<NB, 256, 0, stream>>>(deg, bsum, row_start, cursor, N);
        k_scatter_xcd<<<AB, 256, 0, stream>>>(srci, tgti, cursor, csr, E, NS);
        k_stats_csr<<<SB, 256, 0, stream>>>(uh, vq, row_start, csr, partials, N);
        k_finalize<<<1, 256, 0, stream>>>(partials, SB, gamma, beta, ab, 1.0f / (float)E);
        k_apply_csr<<<AB, 256, 0, stream>>>(uh, vh, row_start, csr, ab, (float*)d_out, N);
    } else {
        const int SBf = 512;
        float* abf      = (float*)d_ws;
        float* partialsf = abf + 64;
        hipMemsetAsync(d_out, 0, (size_t)out_size * sizeof(float), stream);
        k_stats_hist<<<SBf, 256, 0, stream>>>(x, srci, tgti, W, partialsf, E);
        k_finalize<<<1, 256, 0, stream>>>(partialsf, SBf, gamma, beta, abf, 1.0f / (float)E);
        k_apply_atomic<<<(E + 255) / 256, 256, 0, stream>>>(x, srci, tgti, W, abf,
                                                            (float*)d_out, E);
    }
}